// Round 10
// baseline (965.097 us; speedup 1.0000x reference)
//
#include <hip/hip_runtime.h>
#include <math.h>

// FISTA, phase-split 4x, XCD-colocated, L3 exchange — R27.
// R26 (955us) post-mortem: residual SQ_LDS_BANK_CONFLICT 2.82e7 is stage-2's
// y/ylast float4s (thread t at float 8t -> 16 lanes per 4-bank group, 2x
// serialized); exchange = 3 serial L3 hops (~2450 cyc/iter): drain -> counter
// visible+spin -> prepass load. R27:
//  A. y/ylast physical layout split [h=e&4-half][486 float4]: thread t's two
//     float4s at 4t and 1944+4t -> per-instruction bank-groups (l)%8 = all 8
//     -> conflict-free. Stage-1 scalar reads refold exactly:
//     addr = r*216 + wc*24 + ylane2, ylane2 = ((ylane>>2)&1)*1944 +
//     (ylane>>3)*4 + (ylane&3); max 2-way (free). ZERO instruction delta.
//  B. Sentinel-validated exchange (1 L3 hop): Ap slots pre-filled with qNaN
//     SENT (finite conv partials can never equal it). Producers store data
//     fire-and-forget (NO drain, NO flag, NO spin, NO 2 of the 4 barriers);
//     consumers poll their 4 data words until != SENT. 4-deep Ap rotation;
//     producer clears its iter-2 slice back to SENT alongside the store.
//     WAR via DEFERRED counter: tid0 fetch_adds after prepass-sync (signals
//     "block's reads of buf iter&3 done"); writers gate stores+clears on
//     counter >= 4(iter-1) — 2 iterations of slack, pre-satisfied, checked
//     wave-uniform with a loop-top preloaded value.
// Staleness proof (D=4): consumer at iter m polls buf m&3, cleared by each
// producer at m-2 BEFORE its add(m-2) (clears drained by sync1's vmcnt(0)).
// Consumer's gate read saw counter >= 4(m-1) >= includes every add(m-2), and
// its polls issue after that read -> L3 processed every clear first -> polls
// see SENT or fresh iter-m data, never stale. Deadlock-free by induction
// (gate(m) depends only on iter m-2 completion).
// ws grows to ~1.05 MB (4x248832 Ap floats).
//
// Kept from R23-R26: conv weights in LDS [tap][lane][4] b128 (VGPR-hoist
// remats global loads — R24); pk_fma stage-1; DPP+transpose reduce + ONE
// coalesced 27-lane store; stage-2 prefetch; prepass stores r = x - a;
// Wct stride-200.

#define ITERS 200
#define THREADS 576
#define SENTU 0x7FC0DEADu
// d_ws float offsets
#define WGOFF 0          // 19200: [g][t*3+co][lane], q=3 lanes zeroed
#define WCTOFF 19200     // 600: [c(stride 200)][ci*64][p]
#define APOFF 19800      // 4 bufs * 64 img * 972 = 248832 (sentinel-rotated)
#define CNTOFF 268632    // int offsets: 64 images x 64-int padding
// LDS float offsets
#define LY 0             // y: 2 halves x 486 float4 (3888 floats)
#define LYL 3888         // y_last: same layout
#define LA 7776          // r-values: 243 (+1 pad)
#define LXS 8020         // x image slice: 243 (+1 pad)
#define LWG 8264         // conv weights: 25 taps x 64 lanes x 4 (co,pad)
#define LWCT 14664       // Wct: 600 [c*200+ci*64+p]
#define LT 15264         // transpose scratch: 9 waves x 27 rows x stride 20
#define SMEMF 20608      // 82,432 B (> 80 KB -> exactly 1 block/CU)

typedef float f32x2 __attribute__((ext_vector_type(2)));

template <int CTRL>
__device__ __forceinline__ float dpp_add(float x) {
  int moved = __builtin_amdgcn_update_dpp(0, __float_as_int(x), CTRL, 0xF, 0xF, true);
  return x + __int_as_float(moved);
}

// WG[((g*75 + t*3 + co))*64 + lane] = w_conv[8*th+ph][8*tw+pw][ci=q][co]
//   with lane=(q,pl), p = g*16+pl; q==3 -> 0 (dead quadrant).
// WCT2[c*200 + ci*64 + p] = (rh<5 && rw<5) ? w_ct[4-rh][4-rw][ci][c] : 0.
// Ap region: filled with SENT; counters zeroed.
__global__ void k0_init(const float* __restrict__ w_conv,
                        const float* __restrict__ w_ct,
                        float* __restrict__ ws) {
  const int i = blockIdx.x * 256 + threadIdx.x;
  if (i < 19200) {
    const int lane = i & 63;
    const int rest = i >> 6;          // g*75 + t*3 + co
    const int g = rest / 75;
    const int tc = rest - 75 * g;
    const int t = tc / 3;
    const int co = tc - 3 * t;
    const int th = t / 5;
    const int tw = t - 5 * th;
    const int q = lane >> 4;
    const int pl = lane & 15;
    float v = 0.f;
    if (q < 3) {
      const int p = g * 16 + pl;
      const int ph = p >> 3;
      const int pw = p & 7;
      v = w_conv[(((8 * th + ph) * 40 + (8 * tw + pw)) * 3 + q) * 3 + co];
    }
    ws[WGOFF + i] = v;
  }
  if (i < 600) {
    const int c = i / 200;
    const int rem = i - 200 * c;
    float v = 0.f;
    if (rem < 192) {
      const int ci = rem >> 6;
      const int p = rem & 63;
      const int rh = p >> 3;
      const int rw = p & 7;
      if (rh < 5 && rw < 5) v = w_ct[(((4 - rh) * 5 + (4 - rw)) * 3 + ci) * 3 + c];
    }
    ws[WCTOFF + i] = v;
  }
  for (int j = i; j < 248832; j += 80 * 256)
    ((unsigned*)ws)[APOFF + j] = SENTU;
  if (i < 4096) ((int*)ws)[CNTOFF + i] = 0;
}

__global__ __launch_bounds__(THREADS) void fista_split(
    float* __restrict__ ws,
    const float* __restrict__ x, const float* __restrict__ lam,
    const float* __restrict__ b_conv, const float* __restrict__ b_ct,
    float* __restrict__ out) {
  __shared__ __align__(16) float smem[SMEMF];
  const int tid = threadIdx.x;
  const int blk = blockIdx.x;
  const int n = blk & 63;         // image  (XCD colocation: n, n+64, n+128,
  const int g = blk >> 6;         //  n+192 share blk%8)
  const int lane = tid & 63;
  const int wid = tid >> 6;       // wave index (9 waves)
  const int q = lane >> 4;        // ci quadrant (3 = dead)
  const int pl = lane & 15;
  const int ylane = ((q < 3) ? q : 2) * 16 + pl;  // q=3 dupes q=2: broadcast
  // split-half y addressing (change A): lane constant
  const int ylane2 = ((ylane >> 2) & 1) * 1944 + (ylane >> 3) * 4 + (ylane & 3);
  // wave->row perm {0,4,2,3,8,5,6,7,1}: per-SIMD tap-row load balanced (10).
  const int oh = (wid == 0) ? 0 : (wid == 1) ? 4 : (wid == 4) ? 8
               : (wid == 8) ? 1 : wid;

  int* __restrict__ cnt = (int*)ws + CNTOFF + n * 64;
  const float lam_n = lam[n];
  const float bcv = b_conv[tid % 3];   // pre-pass bias (used when tid<243)
  const float bct0 = b_ct[0], bct1 = b_ct[1], bct2 = b_ct[2];

  // ---- stage LDS: zero all, scatter conv weights to [tap][lane][4],
  // copy Wct + x slice ----
  for (int i = tid; i < SMEMF; i += THREADS) smem[i] = 0.f;
  __syncthreads();
  for (int i = tid; i < 4800; i += THREADS) {
    const int lane_i = i & 63;
    const int tc = i >> 6;            // t*3 + co
    const int t_i = tc / 3;
    const int co_i = tc - 3 * t_i;
    smem[LWG + (t_i * 64 + lane_i) * 4 + co_i] = ws[WGOFF + g * 4800 + i];
  }
  for (int i = tid; i < 600; i += THREADS) smem[LWCT + i] = ws[WCTOFF + i];
  if (tid < 243) smem[LXS + tid] = x[n * 243 + tid];
  __syncthreads();

  // stage-2 ownership: thread t<486 owns elements e = 8t .. 8t+7
  const int idx3 = tid >> 1;
  const int cell = idx3 / 3;
  const int c = idx3 - 3 * cell;
  const int cb = 3 * cell;
  const int plb = (tid & 1) * 8;       // p_local base (0 or 8)
  const int pb = g * 16 + plb;         // global p base

  float t = 1.0f;
#pragma unroll 1
  for (int iter = 0; iter < ITERS; ++iter) {
    // WAR-gate preload (2-iter slack; same addr across lanes -> 1 request)
    int gate_seen = __hip_atomic_load(cnt, __ATOMIC_RELAXED,
                                      __HIP_MEMORY_SCOPE_AGENT);

    // ===== stage 1: partial a over this block's 16 phases; wave = oh ==========
    {
      f32x2 a01[9];                // [ow] = (co0, co1)
      float a2[9];                 // [ow] = co2
#pragma unroll
      for (int k = 0; k < 9; ++k) { a01[k].x = 0.f; a01[k].y = 0.f; a2[k] = 0.f; }

#pragma unroll
      for (int th = 0; th < 5; ++th) {
        const int r = oh + th - 2;          // input row
        if (r >= 0 && r <= 8) {
          f32x2 y2[9];                      // broadcast pairs {y,y}
#pragma unroll
          for (int wc = 0; wc < 9; ++wc) {
            const float yv = smem[LY + r * 216 + wc * 24 + ylane2];
            y2[wc].x = yv; y2[wc].y = yv;
          }

#pragma unroll
          for (int tw = 0; tw < 5; ++tw) {
            const float4 wv =
                *(const float4*)&smem[LWG + ((th * 5 + tw) * 64 + lane) * 4];
            f32x2 w01; w01.x = wv.x; w01.y = wv.y;
#pragma unroll
            for (int ow = 0; ow < 9; ++ow) {
              const int col = ow + tw - 2;
              if (col >= 0 && col <= 8) {   // compile-time trim
                a01[ow] += y2[col] * w01;   // v_pk_fma_f32
                a2[ow]  += y2[col].x * wv.z;
              }
            }
          }
        }
      }

      // ---- reduce: 2 DPP stages -> 4-lane sums; masked transpose write ----
      float s4[27];
#pragma unroll
      for (int k = 0; k < 27; ++k) {
        const int ow = k / 3, co = k - 3 * ow;      // compile-time
        const float av = (co == 0) ? a01[ow].x : (co == 1) ? a01[ow].y : a2[ow];
        const float s1 = dpp_add<0x111>(av);        // row_shr:1
        s4[k] = dpp_add<0x112>(s1);                 // row_shr:2 -> 4-group sum
      }
      {
        float* Tw = &smem[LT + wid * 540];
        if ((lane & 3) == 3) {
          const int m = lane >> 2;                  // 0..15
#pragma unroll
          for (int k = 0; k < 27; ++k) Tw[k * 20 + m] = s4[k];
        }
        // ===== WAR gate (rare; wave-uniform; overlaps LDS write latency) ====
        const int gate_target = 4 * (iter - 1);
        while (gate_seen < gate_target)
          gate_seen = __hip_atomic_load(cnt, __ATOMIC_RELAXED,
                                        __HIP_MEMORY_SCOPE_AGENT);
        asm volatile("s_waitcnt lgkmcnt(0)" ::: "memory");
        if (lane < 27) {
          const float4* Tr = (const float4*)&Tw[lane * 20];
          const float4 p0 = Tr[0];
          const float4 p1 = Tr[1];
          const float4 p2 = Tr[2];
          const float4 p3 = Tr[3];
          const float s01 = (p0.x + p0.y) + (p0.z + p0.w);
          const float s23 = (p1.x + p1.y) + (p1.z + p1.w);
          const float s45 = (p2.x + p2.y) + (p2.z + p2.w);
          const float s67 = (p3.x + p3.y) + (p3.z + p3.w);
          const float s = (s01 + s23) + (s45 + s67);
          // data store: fire-and-forget (sentinel scheme needs no drain)
          float* ap = ws + APOFF + (((iter & 3) * 64 + n) * 4 + g) * 243
                      + oh * 27 + lane;
          __hip_atomic_store(ap, s, __ATOMIC_RELAXED, __HIP_MEMORY_SCOPE_AGENT);
          // clear our iter-2 slice back to SENT (gated by same WAR check;
          // drained by sync1's vmcnt before our add -> ordered for D=4 proof)
          if (iter >= 2) {
            unsigned* cp = (unsigned*)ws + APOFF
                + ((((iter - 2) & 3) * 64 + n) * 4 + g) * 243 + oh * 27 + lane;
            __hip_atomic_store(cp, SENTU, __ATOMIC_RELAXED,
                               __HIP_MEMORY_SCOPE_AGENT);
          }
        }
      }
    }

    // ===== stage-2 prefetch: operands -> regs (overlaps the poll) =====
    float4 py0 = {}, py1 = {}, pq0 = {}, pq1 = {};
    float4 w0a = {}, w0b = {}, w1a = {}, w1b = {}, w2a = {}, w2b = {};
    if (tid < 486) {
      py0 = *(const float4*)&smem[LY  + 4 * tid];
      py1 = *(const float4*)&smem[LY  + 1944 + 4 * tid];
      pq0 = *(const float4*)&smem[LYL + 4 * tid];
      pq1 = *(const float4*)&smem[LYL + 1944 + 4 * tid];
      w0a = *(const float4*)&smem[LWCT + c * 200 +   0 + pb];
      w0b = *(const float4*)&smem[LWCT + c * 200 +   4 + pb];
      w1a = *(const float4*)&smem[LWCT + c * 200 +  64 + pb];
      w1b = *(const float4*)&smem[LWCT + c * 200 +  68 + pb];
      w2a = *(const float4*)&smem[LWCT + c * 200 + 128 + pb];
      w2b = *(const float4*)&smem[LWCT + c * 200 + 132 + pb];
    }

    // ===== prepass: poll self-validating data (1 L3 hop), r -> LDS =====
    if (tid < 243) {
      const unsigned* apb = (const unsigned*)ws + APOFF
                            + ((iter & 3) * 64 + n) * 972;
      unsigned u0, u1, u2, u3;
      do {
        u0 = __hip_atomic_load(apb + tid,       __ATOMIC_RELAXED,
                               __HIP_MEMORY_SCOPE_AGENT);
        u1 = __hip_atomic_load(apb + 243 + tid, __ATOMIC_RELAXED,
                               __HIP_MEMORY_SCOPE_AGENT);
        u2 = __hip_atomic_load(apb + 486 + tid, __ATOMIC_RELAXED,
                               __HIP_MEMORY_SCOPE_AGENT);
        u3 = __hip_atomic_load(apb + 729 + tid, __ATOMIC_RELAXED,
                               __HIP_MEMORY_SCOPE_AGENT);
      } while ((u0 == SENTU) | (u1 == SENTU) | (u2 == SENTU) | (u3 == SENTU));
      const float a0  = __uint_as_float(u0);
      const float a1  = __uint_as_float(u1);
      const float a2v = __uint_as_float(u2);
      const float a3  = __uint_as_float(u3);
      smem[LA + tid] = smem[LXS + tid] - (a0 + a1 + a2v + a3 + bcv);
    }
    __syncthreads();   // sync1: LA ready; all stage-1 y reads done;
                       // implicit vmcnt(0) drains our stores+clears
    if (tid == 0)      // deferred WAR signal: this block's buf reads done
      __hip_atomic_fetch_add(cnt, 1, __ATOMIC_RELAXED, __HIP_MEMORY_SCOPE_AGENT);

    const float tn = (1.0f + sqrtf(1.0f + 4.0f * t * t)) * 0.5f;
    const float beta = (t - 1.0f) / tn;    // beta_0 = 0
    t = tn;

    // ===== stage 2: 8 elements/thread, operands prefetched =====
    const bool lastit = (iter == ITERS - 1);
    if (tid < 486) {
      const float r0  = smem[LA + cb + 0];
      const float r1  = smem[LA + cb + 1];
      const float r2v = smem[LA + cb + 2];
      const float bct = (c == 0) ? bct0 : ((c == 1) ? bct1 : bct2);

      const float wct0[8] = {w0a.x, w0a.y, w0a.z, w0a.w, w0b.x, w0b.y, w0b.z, w0b.w};
      const float wct1[8] = {w1a.x, w1a.y, w1a.z, w1a.w, w1b.x, w1b.y, w1b.z, w1b.w};
      const float wct2[8] = {w2a.x, w2a.y, w2a.z, w2a.w, w2b.x, w2b.y, w2b.z, w2b.w};
      const float yv[8]   = {py0.x, py0.y, py0.z, py0.w, py1.x, py1.y, py1.z, py1.w};
      float yn[8];
#pragma unroll
      for (int j = 0; j < 8; ++j) {
        const float re = bct + r0 * wct0[j] + r1 * wct1[j] + r2v * wct2[j];
        const float wvv = yv[j] - re;
        yn[j] = fmaxf(wvv - lam_n, 0.f) - fmaxf(-wvv - lam_n, 0.f);
      }

      if (!lastit) {
        const float ylv[8] = {pq0.x, pq0.y, pq0.z, pq0.w, pq1.x, pq1.y, pq1.z, pq1.w};
        float4 s0, s1, m0, m1;
        s0.x = yn[0]; s0.y = yn[1]; s0.z = yn[2]; s0.w = yn[3];
        s1.x = yn[4]; s1.y = yn[5]; s1.z = yn[6]; s1.w = yn[7];
        m0.x = yn[0] + beta * (yn[0] - ylv[0]);
        m0.y = yn[1] + beta * (yn[1] - ylv[1]);
        m0.z = yn[2] + beta * (yn[2] - ylv[2]);
        m0.w = yn[3] + beta * (yn[3] - ylv[3]);
        m1.x = yn[4] + beta * (yn[4] - ylv[4]);
        m1.y = yn[5] + beta * (yn[5] - ylv[5]);
        m1.z = yn[6] + beta * (yn[6] - ylv[6]);
        m1.w = yn[7] + beta * (yn[7] - ylv[7]);
        *(float4*)&smem[LYL + 4 * tid] = s0;
        *(float4*)&smem[LYL + 1944 + 4 * tid] = s1;
        *(float4*)&smem[LY  + 4 * tid] = m0;
        *(float4*)&smem[LY  + 1944 + 4 * tid] = m1;
      } else {
        const int part = pb >> 3;           // p>>3 constant over j
        const int qh = cell / 9;
        const int qw = cell - 9 * qh;
        const int ih = 8 * qh + part;
        float* op = out + ((n * 72 + ih) * 72 + 8 * qw) * 3 + c;
#pragma unroll
        for (int j = 0; j < 8; ++j) op[3 * j] = yn[j];
      }
    }
    __syncthreads();   // sync2: y stable before next stage-1
  }
}

extern "C" void kernel_launch(void* const* d_in, const int* in_sizes, int n_in,
                              void* d_out, int out_size, void* d_ws, size_t ws_size,
                              hipStream_t stream) {
  const float* x      = (const float*)d_in[0];
  const float* lam    = (const float*)d_in[1];
  const float* w_conv = (const float*)d_in[2];
  const float* b_conv = (const float*)d_in[3];
  const float* w_ct   = (const float*)d_in[4];
  const float* b_ct   = (const float*)d_in[5];
  float* out = (float*)d_out;
  float* ws  = (float*)d_ws;  // needs ~1.05 MB (4-deep Ap rotation)

  hipLaunchKernelGGL(k0_init, dim3(80), dim3(256), 0, stream, w_conv, w_ct, ws);
  hipLaunchKernelGGL(fista_split, dim3(256), dim3(THREADS), 0, stream,
                     ws, x, lam, b_conv, b_ct, out);
}